// Round 9
// baseline (7331.472 us; speedup 1.0000x reference)
//
#include <hip/hip_runtime.h>
#include <hip/hip_bf16.h>
#include <stdint.h>

// Problem constants
#define S_INPUT  1024
#define S_HIDDEN 2048
#define S_SEQ    256
#define S_BATCH  256
#define NWG_P    96     // persistent grid: 64 A-task + 32 B-task WGs

typedef __attribute__((ext_vector_type(8))) short bf16x8;   // 8 bf16 = 4 VGPRs
typedef __attribute__((ext_vector_type(4))) float f32x4;    // MFMA accumulator

// CPol bits: gfx950 SC0|SC1 = bypass L1+L2, read/write at coherence point.
#define AUX_CACHED 0
#define AUX_SYS    17

// LDS geometry: slot = 8KB A-tile (64x64 bf16) + 16KB B-tile (128x64 bf16).
// 4 slots = 98304 B total — the size PROVEN to launch under
// hipLaunchCooperativeKernel + graph capture (R6). 120KB (R7) silently
// failed the cooperative-launch validation -> kernel never ran.
#define SLOT_BYTES 24576
#define LDS_BYTES  (SLOT_BYTES*4)   // 96 KB

__device__ __forceinline__ short f2bf(float f){
  union { float f; unsigned u; } v; v.f = f;
  unsigned r = v.u + 0x7fffu + ((v.u >> 16) & 1u);   // round-nearest-even
  return (short)(r >> 16);
}

// tanh via one v_exp_f32 + v_rcp_f32; exact at saturation.
__device__ __forceinline__ float tanh_fast(float x){
  float e = __expf(2.0f * x);
  return 1.0f - 2.0f / (e + 1.0f);
}

// ---------------------------------------------------------------------------
// All-gather flag barrier (no root WG, no generation round-trip).
// bar[(1+wg)*16] = per-WG arrival counter (64B apart). Each WG: drain vmcnt
// (h stores at coherence point), store own flag (relaxed system/uncached),
// then ALL WGs poll ALL 96 flags until >= ep. Flags monotonic -> no reset.
// No release/acquire -> no wbl2/inv -> weights stay L2-resident all run.
// Max skew is 1 step (each WG waits for all at every step), so the h
// double-buffer is race-free.
// ---------------------------------------------------------------------------
__device__ __forceinline__ void step_barrier(unsigned* bar, int ep, int bid)
{
  asm volatile("s_waitcnt vmcnt(0) lgkmcnt(0)" ::: "memory");
  __syncthreads();
  if (threadIdx.x == 0)
    __hip_atomic_store(bar + (size_t)(1 + bid)*16, (unsigned)ep,
                       __ATOMIC_RELAXED, __HIP_MEMORY_SCOPE_SYSTEM);
  for (;;){
    int ok = 1;
    if (threadIdx.x < NWG_P){
      unsigned v = __hip_atomic_load(bar + (size_t)(1 + threadIdx.x)*16,
                                     __ATOMIC_RELAXED, __HIP_MEMORY_SCOPE_SYSTEM);
      ok = (v >= (unsigned)ep);
    }
    if (__syncthreads_and(ok)) break;
    __builtin_amdgcn_s_sleep(1);
  }
}

// ---------------------------------------------------------------------------
// 64x128x(K) bf16 GEMM core, B^T layout: out[m][n] = sum_k A[m][k]*B[n][k].
// 4 waves (2x2), each wave owns 32x64 (acc 2x4). 4-slot LDS ring, prefetch
// distance 3, counted vmcnt (6 loads/stage/wave), raw s_barrier. AUXA=17
// for h (uncached, always fresh); B cached (L2-resident weights).
// ---------------------------------------------------------------------------
template<int AUXA>
__device__ __forceinline__ void gemm_core(const short* __restrict__ A, int lda,
                                          const short* __restrict__ B, int ldb,
                                          int bm, int bn, int ktiles,
                                          f32x4 acc[2][4], char* lds)
{
  const int tid  = threadIdx.x;
  const int lane = tid & 63;
  const int wid  = tid >> 6;
  const int wm   = (wid >> 1) & 1;
  const int wn   = wid & 1;
  const int r15  = lane & 15;
  const int hi   = lane >> 4;
  const int ra0  = wm*32 + r15,  ra1 = ra0 + 16;   // A rows (m) in tile
  const int rbb  = wn*64 + r15;                    // B row base (n) in tile

  // A staging: 512 chunks (8KB), 2/thread. B staging: 1024 chunks (16KB), 4/thread.
  const int ca0 = tid, ca1 = tid + 256;
  const int ar0 = ca0 >> 3, ar1 = ca1 >> 3;
  const int ae0 = ((((ca0 & 7) << 4) ^ ((ar0 & 7) << 4)) >> 1);
  const int ae1 = ((((ca1 & 7) << 4) ^ ((ar1 & 7) << 4)) >> 1);
  const short* pa0 = A + (size_t)(bm + ar0)*lda + ae0;
  const short* pa1 = A + (size_t)(bm + ar1)*lda + ae1;
  const short* pb[4];
  int cb[4];
  #pragma unroll
  for (int j = 0; j < 4; ++j){
    cb[j] = tid + j*256;
    int br = cb[j] >> 3;
    int be = ((((cb[j] & 7) << 4) ^ ((br & 7) << 4)) >> 1);
    pb[j] = B + (size_t)(bn + br)*ldb + be;
  }

  #define STAGE(kt, s) do { \
    const int _ko = (kt)*64; char* _sa = lds + (s)*SLOT_BYTES; char* _sb = _sa + 8192; \
    __builtin_amdgcn_global_load_lds((const __attribute__((address_space(1))) void*)(pa0 + _ko), \
        (__attribute__((address_space(3))) void*)(_sa + ca0*16), 16, 0, AUXA); \
    __builtin_amdgcn_global_load_lds((const __attribute__((address_space(1))) void*)(pa1 + _ko), \
        (__attribute__((address_space(3))) void*)(_sa + ca1*16), 16, 0, AUXA); \
    __builtin_amdgcn_global_load_lds((const __attribute__((address_space(1))) void*)(pb[0] + _ko), \
        (__attribute__((address_space(3))) void*)(_sb + cb[0]*16), 16, 0, AUX_CACHED); \
    __builtin_amdgcn_global_load_lds((const __attribute__((address_space(1))) void*)(pb[1] + _ko), \
        (__attribute__((address_space(3))) void*)(_sb + cb[1]*16), 16, 0, AUX_CACHED); \
    __builtin_amdgcn_global_load_lds((const __attribute__((address_space(1))) void*)(pb[2] + _ko), \
        (__attribute__((address_space(3))) void*)(_sb + cb[2]*16), 16, 0, AUX_CACHED); \
    __builtin_amdgcn_global_load_lds((const __attribute__((address_space(1))) void*)(pb[3] + _ko), \
        (__attribute__((address_space(3))) void*)(_sb + cb[3]*16), 16, 0, AUX_CACHED); \
  } while (0)

  STAGE(0, 0);
  if (ktiles > 1) STAGE(1, 1);
  if (ktiles > 2) STAGE(2, 2);

  for (int t = 0; t < ktiles; ++t){
    const int rem = ktiles - 1 - t;
    if (rem >= 2)      asm volatile("s_waitcnt vmcnt(12)" ::: "memory");
    else if (rem == 1) asm volatile("s_waitcnt vmcnt(6)"  ::: "memory");
    else               asm volatile("s_waitcnt vmcnt(0)"  ::: "memory");
    asm volatile("s_barrier" ::: "memory");   // raw: prefetch stays in flight
    if (t + 3 < ktiles) STAGE(t + 3, (t + 3) & 3);
    const char* as = lds + (t & 3)*SLOT_BYTES;
    const char* bs = as + 8192;
    #pragma unroll
    for (int kk = 0; kk < 2; ++kk){
      const int kb = kk*64 + hi*16;
      bf16x8 a0 = *(const bf16x8*)(as + ra0*128 + (kb ^ ((ra0 & 7) << 4)));
      bf16x8 a1 = *(const bf16x8*)(as + ra1*128 + (kb ^ ((ra1 & 7) << 4)));
      #pragma unroll
      for (int ni = 0; ni < 4; ++ni){
        const int rb = rbb + ni*16;
        bf16x8 b = *(const bf16x8*)(bs + rb*128 + (kb ^ ((rb & 7) << 4)));
        acc[0][ni] = __builtin_amdgcn_mfma_f32_16x16x32_bf16(a0, b, acc[0][ni], 0, 0, 0);
        acc[1][ni] = __builtin_amdgcn_mfma_f32_16x16x32_bf16(a1, b, acc[1][ni], 0, 0, 0);
      }
    }
  }
  #undef STAGE
}

// ---------------------------------------------------------------------------
// A-task epilogue: tanh + bf16; repack through LDS so each thread emits 4
// contiguous 16B chunks as 8B uncached atomics (write-combining friendly).
// C/D layout (m89): within a frag, col = lane&15, row = (lane>>4)*4 + i.
// Race-free: vmcnt(0) was drained at the last gemm iteration (no in-flight
// DMA into LDS), and the leading __syncthreads covers cross-wave reads.
// ---------------------------------------------------------------------------
__device__ __forceinline__ void epi_h(const f32x4 acc[2][4], short* dst,
                                      const float* __restrict__ cv,
                                      int bm, int bn, char* lds)
{
  const int lane = threadIdx.x & 63, wid = threadIdx.x >> 6;
  const int wm = (wid>>1)&1, wn = wid&1, r15 = lane&15, hi = lane>>4;
  __syncthreads();   // all waves done reading the last pipeline slot
  #pragma unroll
  for (int mi = 0; mi < 2; ++mi)
    #pragma unroll
    for (int ni = 0; ni < 4; ++ni){
      int lc = wn*64 + ni*16 + r15;
      float cb = cv[bn + lc];
      #pragma unroll
      for (int i = 0; i < 4; ++i){
        int lr = wm*32 + mi*16 + hi*4 + i;
        *(short*)(lds + lr*256 + lc*2) = f2bf(tanh_fast(acc[mi][ni][i] + cb));
      }
    }
  __syncthreads();
  const int tid = threadIdx.x;
  #pragma unroll
  for (int j = 0; j < 4; ++j){
    int c = tid*4 + j;             // 0..1023 chunks of 16B, row-major [64][128]
    int lr = c >> 4, lc8 = c & 15;
    uint64_t w0 = *(const uint64_t*)(lds + c*16);
    uint64_t w1 = *(const uint64_t*)(lds + c*16 + 8);
    uint64_t* g = (uint64_t*)(dst + (size_t)(bm + lr)*S_HIDDEN + bn + lc8*8);
    __hip_atomic_store(g,     w0, __ATOMIC_RELAXED, __HIP_MEMORY_SCOPE_SYSTEM);
    __hip_atomic_store(g + 1, w1, __ATOMIC_RELAXED, __HIP_MEMORY_SCOPE_SYSTEM);
  }
}

// B-task epilogue: f32 out, nontemporal (don't evict L2-resident weights).
__device__ __forceinline__ void epi_out(const f32x4 acc[2][4], float* outp,
                                        const float* __restrict__ bfc,
                                        int bm, int bn)
{
  const int lane = threadIdx.x & 63, wid = threadIdx.x >> 6;
  const int wm = (wid>>1)&1, wn = wid&1, r15 = lane&15, hi = lane>>4;
  #pragma unroll
  for (int mi = 0; mi < 2; ++mi)
    #pragma unroll
    for (int ni = 0; ni < 4; ++ni){
      int n = bn + wn*64 + ni*16 + r15;
      float cb = bfc[n];
      #pragma unroll
      for (int i = 0; i < 4; ++i){
        int m = bm + wm*32 + mi*16 + hi*4 + i;
        __builtin_nontemporal_store(acc[mi][ni][i] + cb,
                                    &outp[(size_t)m*(S_SEQ*S_INPUT) + n]);
      }
    }
}

// ---------------------------------------------------------------------------
// Prologue kernels
// ---------------------------------------------------------------------------
__global__ __launch_bounds__(256) void k_build_wcat(const float* __restrict__ Wih,
                                                    const float* __restrict__ Whh,
                                                    short* __restrict__ Wcat)
{
  int j = blockIdx.x;
  for (int i = threadIdx.x; i < 3072; i += 256){
    float f = (i < 1024) ? Wih[(size_t)j*1024 + i] : Whh[(size_t)j*2048 + (i-1024)];
    Wcat[(size_t)j*3072 + i] = f2bf(f);
  }
}

__global__ __launch_bounds__(256) void k_build_acat(const float* __restrict__ x,
                                                    const float* __restrict__ h0,
                                                    short* __restrict__ Acat)
{
  int b = blockIdx.x;
  for (int i = threadIdx.x; i < 3072; i += 256){
    float f = (i < 1024) ? x[(size_t)b*1024 + i] : h0[(size_t)b*2048 + (i-1024)];
    Acat[(size_t)b*3072 + i] = f2bf(f);
  }
}

__global__ __launch_bounds__(256) void k_trans_wfc(const float* __restrict__ Wfc,
                                                   short* __restrict__ Wfcb,
                                                   short* __restrict__ WfcT)
{
  __shared__ float t[32][33];
  int i0 = blockIdx.x*32, k0 = blockIdx.y*32;
  int c = threadIdx.x & 31, r = threadIdx.x >> 5;
  #pragma unroll
  for (int rr = 0; rr < 4; ++rr){
    int i = i0 + r*4 + rr, k = k0 + c;
    float v = Wfc[(size_t)i*2048 + k];
    Wfcb[(size_t)i*2048 + k] = f2bf(v);
    t[r*4+rr][c] = v;
  }
  __syncthreads();
  #pragma unroll
  for (int rr = 0; rr < 4; ++rr){
    int k = k0 + r*4 + rr, i = i0 + c;
    WfcT[(size_t)k*1024 + i] = f2bf(t[c][r*4+rr]);
  }
}

__global__ __launch_bounds__(256) void k_cvec(const float* __restrict__ Wih,
                                              const float* __restrict__ bfc,
                                              const float* __restrict__ bih,
                                              const float* __restrict__ bhh,
                                              float* __restrict__ brnn,
                                              float* __restrict__ cvec)
{
  __shared__ float red[256];
  int j = blockIdx.x;
  float s = 0.f;
  for (int i = threadIdx.x; i < 1024; i += 256) s += Wih[(size_t)j*1024 + i]*bfc[i];
  red[threadIdx.x] = s; __syncthreads();
  for (int st = 128; st > 0; st >>= 1){
    if (threadIdx.x < st) red[threadIdx.x] += red[threadIdx.x+st];
    __syncthreads();
  }
  if (threadIdx.x == 0){
    float br = bih[j] + bhh[j];
    brnn[j] = br;
    cvec[j] = br + red[0];
  }
}

// Wcomb[j][k] = bf16( sum_i Wih[j][i]*Wfc[i][k] + Whh[j][k] )  (2048x2048)
__global__ __launch_bounds__(256) void k_wcomb(const short* __restrict__ Wcat,
                                               const short* __restrict__ WfcT,
                                               const float* __restrict__ Whh,
                                               short* __restrict__ Wcomb)
{
  __shared__ char lds[LDS_BYTES];
  f32x4 acc[2][4] = {};
  int bid = blockIdx.x;                 // 512 WGs: 32 m-panels x 16 n-panels
  int xcd = bid & 7, j = bid >> 3;      // j 0..63
  int np = xcd*2 + (j & 1);             // 0..15
  int mp = j >> 1;                      // 0..31
  int bm = mp*64, bn = np*128;
  gemm_core<AUX_CACHED>(Wcat, 3072, WfcT, 1024, bm, bn, 16, acc, lds);
  const int lane = threadIdx.x & 63, wid = threadIdx.x >> 6;
  const int wm = (wid>>1)&1, wn = wid&1, r15 = lane&15, hi = lane>>4;
  #pragma unroll
  for (int mi = 0; mi < 2; ++mi)
    #pragma unroll
    for (int ni = 0; ni < 4; ++ni){
      int n = bn + wn*64 + ni*16 + r15;
      #pragma unroll
      for (int i = 0; i < 4; ++i){
        int m = bm + wm*32 + mi*16 + hi*4 + i;
        Wcomb[(size_t)m*2048 + n] = f2bf(acc[mi][ni][i] + Whh[(size_t)m*2048 + n]);
      }
    }
}

// ---------------------------------------------------------------------------
// Persistent step kernel: 96 WGs.
// WGs 0..63 (A): h_{t+1} = tanh(h_t @ Wcomb^T + cvec)  [uncached packed store]
// WGs 64..95 (B): out_{t-1} = h_t @ Wfc^T + b_fc       [nontemporal store]
// h reads: AUX_SYS staging (fresh, L2-bypassing); weights cached/L2-resident.
// XCD panel map (bid&7): Wcomb slice 1MB + Wfc slice per XCD.
// ---------------------------------------------------------------------------
__global__ __launch_bounds__(256) void k_persist(
    const short* __restrict__ Acat, const short* __restrict__ Wcat,
    const float* __restrict__ brnn,
    const short* __restrict__ Wcomb, const float* __restrict__ cvec,
    const short* __restrict__ Wfcb, const float* __restrict__ bfc,
    short* __restrict__ hb0, short* __restrict__ hb1,
    float* __restrict__ out, unsigned* __restrict__ bar)
{
  __shared__ char lds[LDS_BYTES];
  const int bid = blockIdx.x;

  // A-task coords (bid < 64): 4 m-panels x 16 n-panels
  const int axcd = bid & 7, aj = bid >> 3;          // aj 0..7
  const int abm = (aj >> 1) * 64;                   // 0..192
  const int abn = (axcd*2 + (aj & 1)) * 128;        // 0..1920
  // B-task coords (bid >= 64): 4 m-panels x 8 n-panels
  const int b2 = bid - 64;
  const int bbm = (b2 >> 3) * 64;                   // 0..192
  const int bbn = (b2 & 7) * 128;                   // 0..896

  int ep = 1;

  // ---- t = 0: h1 = tanh([x0|h0] @ [Wih|Whh]^T + brnn) (cached inputs) ----
  if (bid < 64){
    f32x4 acc[2][4] = {};
    gemm_core<AUX_CACHED>(Acat, 3072, Wcat, 3072, abm, abn, 48, acc, lds);
    epi_h(acc, hb0, brnn, abm, abn, lds);
  }
  step_barrier(bar, ep++, bid);

  const short* hc = hb0;
  short*       hn = hb1;
  for (int t = 1; t <= 255; ++t){
    if (bid < 64){
      f32x4 acc[2][4] = {};
      gemm_core<AUX_SYS>(hc, S_HIDDEN, Wcomb, S_HIDDEN, abm, abn, 32, acc, lds);
      epi_h(acc, hn, cvec, abm, abn, lds);
    } else {
      f32x4 acc[2][4] = {};
      gemm_core<AUX_SYS>(hc, S_HIDDEN, Wfcb, S_HIDDEN, bbm, bbn, 32, acc, lds);
      epi_out(acc, out + (size_t)(t-1)*S_INPUT, bfc, bbm, bbn);
    }
    step_barrier(bar, ep++, bid);
    const short* tmp = hc; hc = hn; hn = (short*)tmp;
  }

  // ---- t = 256: out_255 = h_256 @ Wfc^T + b_fc (B-WGs) ----
  if (bid >= 64){
    f32x4 acc[2][4] = {};
    gemm_core<AUX_SYS>(hc, S_HIDDEN, Wfcb, S_HIDDEN, bbm, bbn, 32, acc, lds);
    epi_out(acc, out + (size_t)255*S_INPUT, bfc, bbm, bbn);
  }
}

// ---------------------------------------------------------------------------
extern "C" void kernel_launch(void* const* d_in, const int* in_sizes, int n_in,
                              void* d_out, int out_size, void* d_ws, size_t ws_size,
                              hipStream_t stream)
{
  const float* x   = (const float*)d_in[0];   // (256,1,1024)
  const float* h0  = (const float*)d_in[1];   // (1,256,2048)
  const float* Wih = (const float*)d_in[2];   // (2048,1024)
  const float* Whh = (const float*)d_in[3];   // (2048,2048)
  const float* bih = (const float*)d_in[4];   // (2048)
  const float* bhh = (const float*)d_in[5];   // (2048)
  const float* Wfc = (const float*)d_in[6];   // (1024,2048)
  const float* bfc = (const float*)d_in[7];   // (1024)
  float* out = (float*)d_out;                 // (256,256,1024) f32

  char* ws = (char*)d_ws;
  size_t off = 0;
  auto alloc = [&](size_t bytes) -> void* {
    void* p = ws + off;
    off += (bytes + 255) & ~(size_t)255;
    return p;
  };
  short* Wcat = (short*)alloc((size_t)2048*3072*2);   // [W_ih | W_hh] bf16
  short* Acat = (short*)alloc((size_t)256*3072*2);    // [x0 | h0] bf16
  short* WfcT = (short*)alloc((size_t)2048*1024*2);   // W_fc^T bf16
  short* Wfcb = (short*)alloc((size_t)1024*2048*2);   // W_fc bf16
  short* Wcb  = (short*)alloc((size_t)2048*2048*2);   // Wcomb bf16
  short* hb0  = (short*)alloc((size_t)256*2048*2);
  short* hb1  = (short*)alloc((size_t)256*2048*2);
  float* brnn = (float*)alloc(2048*4);
  float* cvec = (float*)alloc(2048*4);
  unsigned* bar = (unsigned*)alloc(16384);
  (void)ws_size; (void)in_sizes; (void)n_in; (void)out_size;

  // Zero barrier flags (captured in graph; flags monotonic within a launch)
  hipMemsetAsync(bar, 0, 16384, stream);

  // Prologue
  k_build_wcat<<<2048, 256, 0, stream>>>(Wih, Whh, Wcat);
  k_build_acat<<<256, 256, 0, stream>>>(x, h0, Acat);
  k_trans_wfc<<<dim3(32, 64), 256, 0, stream>>>(Wfc, Wfcb, WfcT);
  k_cvec<<<2048, 256, 0, stream>>>(Wih, bfc, bih, bhh, brnn, cvec);
  k_wcomb<<<512, 256, 0, stream>>>(Wcat, WfcT, Whh, Wcb);

  // One persistent cooperative kernel for all 256 steps
  void* args[] = { (void*)&Acat, (void*)&Wcat, (void*)&brnn,
                   (void*)&Wcb,  (void*)&cvec,
                   (void*)&Wfcb, (void*)&bfc,
                   (void*)&hb0,  (void*)&hb1,
                   (void*)&out,  (void*)&bar };
  hipLaunchCooperativeKernel((const void*)k_persist, dim3(NWG_P), dim3(256),
                             args, 0, stream);
}